// Round 4
// baseline (285.629 us; speedup 1.0000x reference)
//
#include <hip/hip_runtime.h>
#include <hip/hip_bf16.h>

#define BB 16
#define NN 1024
#define HH 768
#define NEG_INF_ -9.0e15f
#define SLOPE_ 0.2f

typedef __bf16 bh8 __attribute__((ext_vector_type(8)));
typedef __bf16 bh4 __attribute__((ext_vector_type(4)));
typedef float f4 __attribute__((ext_vector_type(4)));
typedef unsigned int u32;
typedef unsigned long long u64;

// ---------------- wave-level reductions ----------------

__device__ __forceinline__ float wave_sum0(float v) {       // result valid in lane 0
    #pragma unroll
    for (int off = 32; off > 0; off >>= 1) v += __shfl_down(v, off, 64);
    return v;
}
__device__ __forceinline__ float wave_sum_all(float v) {
    #pragma unroll
    for (int off = 1; off < 64; off <<= 1) v += __shfl_xor(v, off, 64);
    return v;
}
__device__ __forceinline__ float wave_max_all(float v) {
    #pragma unroll
    for (int off = 1; off < 64; off <<= 1) v = fmaxf(v, __shfl_xor(v, off, 64));
    return v;
}

// ---------------- async global->LDS 16B ----------------

__device__ __forceinline__ void gl_lds16(const void* g, void* l) {
    __builtin_amdgcn_global_load_lds(
        (const __attribute__((address_space(1))) u32*)g,
        (__attribute__((address_space(3))) u32*)l, 16, 0, 0);
}

// ---------------- kernel 1: prep+xt merged ----------------
// grid 16384 x 256.
//  blocks 0..4095   : adj bit-pack (softmax mask) + adjb bf16 densify (gemm A operand;
//                     adj is exactly {0.0,1.0} -> bf16-exact) + wa (blocks<192) + s-zero.
//  blocks 4096..    : xT transpose tiles (f32->bf16), 32x32, independent of the rest.

__global__ __launch_bounds__(256) void prep_xt_kernel(const float* __restrict__ adj,
                                                      const float* __restrict__ W,
                                                      const float* __restrict__ a,
                                                      const float* __restrict__ x,
                                                      u64* __restrict__ bits,
                                                      __bf16* __restrict__ adjb,
                                                      __bf16* __restrict__ xT,
                                                      float* __restrict__ wa1,
                                                      float* __restrict__ wa2,
                                                      float* __restrict__ s1,
                                                      float* __restrict__ s2) {
    __shared__ __bf16 T[32][36];
    const int bid = blockIdx.x;
    const int tid = threadIdx.x;
    const int wave = tid >> 6, lane = tid & 63;

    if (bid < 4096) {
        const int gid = bid * 256 + tid;
        if (gid < BB * NN) { s1[gid] = 0.f; s2[gid] = 0.f; }   // d_ws poisoned; gemm accumulates

        // ---- bit-pack + bf16-densify one adj row per wave ----
        const int row = bid * 4 + wave;
        const float* ar = adj + (size_t)row * NN;
        __bf16* abr = adjb + (size_t)row * NN;
        const int seg = lane >> 4;
        const int sh = (lane & 15) * 4;
        #pragma unroll
        for (int i = 0; i < 4; i++) {
            const int j = lane * 4 + i * 256;           // 4 consecutive columns
            const float4 av = *(const float4*)(ar + j);
            bh4 o = { (__bf16)av.x, (__bf16)av.y, (__bf16)av.z, (__bf16)av.w };
            *(bh4*)(abr + j) = o;
            u32 nib = (av.x > 1e-6f ? 1u : 0u) | (av.y > 1e-6f ? 2u : 0u)
                    | (av.z > 1e-6f ? 4u : 0u) | (av.w > 1e-6f ? 8u : 0u);
            u64 word = (u64)nib << sh;
            word |= __shfl_xor(word, 8, 16);
            word |= __shfl_xor(word, 4, 16);
            word |= __shfl_xor(word, 2, 16);
            word |= __shfl_xor(word, 1, 16);
            if ((lane & 15) == 0) bits[(size_t)row * 16 + i * 4 + seg] = word;
        }

        // ---- wa = W @ a1|a2 (one wave per f), blocks 0..191 only ----
        if (bid < 192) {
            const int f = bid * 4 + wave;
            const float* Wr = W + (size_t)f * HH;
            float v1 = 0.f, v2 = 0.f;
            #pragma unroll
            for (int i = 0; i < 3; i++) {
                const int h = lane * 4 + i * 256;
                const float4 w  = *(const float4*)(Wr + h);
                const float4 a1 = *(const float4*)(a + h);
                const float4 a2 = *(const float4*)(a + HH + h);
                v1 += w.x * a1.x + w.y * a1.y + w.z * a1.z + w.w * a1.w;
                v2 += w.x * a2.x + w.y * a2.y + w.z * a2.z + w.w * a2.w;
            }
            v1 = wave_sum0(v1);
            v2 = wave_sum0(v2);
            if (lane == 0) { wa1[f] = v1; wa2[f] = v2; }
        }
    } else {
        // ---- xT transpose tile ----
        const int u = bid - 4096;
        const int ht = u % 24;
        const int nt = (u / 24) & 31;
        const int b  = u / (24 * 32);
        const int r = tid >> 3;          // n within tile (0..31)
        const int c = (tid & 7) * 4;     // h within tile (0..28)
        const float4 v = *(const float4*)(x + ((size_t)b * NN + nt * 32 + r) * HH + ht * 32 + c);
        T[r][c + 0] = (__bf16)v.x; T[r][c + 1] = (__bf16)v.y;
        T[r][c + 2] = (__bf16)v.z; T[r][c + 3] = (__bf16)v.w;

        __syncthreads();
        const int h = tid >> 3;          // h within tile
        const int nc = (tid & 7) * 4;    // n within tile
        bh4 o = { T[nc + 0][h], T[nc + 1][h], T[nc + 2][h], T[nc + 3][h] };
        *(bh4*)(xT + ((size_t)b * HH + ht * 32 + h) * NN + nt * 32 + nc) = o;
    }
}

// ---------------- kernel 2: node_vec = adj @ x -- DENSE bf16 MFMA (m97 structure) ----------------
// grid (6,8,BB) x 256. A (adjb) and B (xT) both staged per K-step via global_load_lds
// width-16 with XOR swizzle (slot (r,j) <- global chunk j^(r&7)); fragments read as
// conflict-free ds_read_b128. Replaces the bits+LUT path: no byte-extract VALU chain,
// no per-lane LUT gathers (was 3.08M bank-conflict cycles/dispatch). LDS 32 KB.
// Epilogue: C write + s1/s2 = node_vec @ wa (16-lane shuffle reduce -> 1 atomic/row-half).

__global__ __launch_bounds__(256) void gemm_dense(const __bf16* __restrict__ adjb,
                                                  const __bf16* __restrict__ xT,
                                                  const float* __restrict__ wa1,
                                                  const float* __restrict__ wa2,
                                                  float* __restrict__ out,
                                                  float* __restrict__ s1,
                                                  float* __restrict__ s2) {
    __shared__ __bf16 As[128 * 64];       // 16 KB
    __shared__ __bf16 Bs[128 * 64];       // 16 KB
    const int b = blockIdx.z, bm = blockIdx.y, bn = blockIdx.x;
    const int tid = threadIdx.x, lane = tid & 63, wave = tid >> 6;
    const int wr = (wave >> 1) << 6;
    const int wc = (wave & 1) << 6;
    const int quad = lane >> 4, l16 = lane & 15;

    const __bf16* Ab = adjb + ((size_t)b * NN + bm * 128) * NN;   // A rows: output rows
    const __bf16* Xb = xT   + ((size_t)b * HH + bn * 128) * NN;   // B rows: features

    // per-thread staging geometry (dest is lane-linear: byte offset c*16 -- m104-safe)
    const __bf16* aSrc[4]; const __bf16* bSrc[4]; int dOff[4];
    #pragma unroll
    for (int it = 0; it < 4; it++) {
        const int c = tid + 256 * it;
        const int r = c >> 3, j = c & 7, kc = j ^ (r & 7);
        aSrc[it] = Ab + (size_t)r * NN + kc * 8;
        bSrc[it] = Xb + (size_t)r * NN + kc * 8;
        dOff[it] = c * 8;                 // element offset (=16B per thread-chunk)
    }

    f4 acc[4][4];
    #pragma unroll
    for (int i = 0; i < 4; i++)
        #pragma unroll
        for (int j = 0; j < 4; j++)
            acc[i][j] = (f4){0.f, 0.f, 0.f, 0.f};

    for (int kt = 0; kt < NN; kt += 64) {
        #pragma unroll
        for (int it = 0; it < 4; it++) {
            gl_lds16(aSrc[it] + kt, &As[dOff[it]]);
            gl_lds16(bSrc[it] + kt, &Bs[dOff[it]]);
        }
        __syncthreads();   // drains vmcnt(0): A+B tiles ready

        #pragma unroll
        for (int s = 0; s < 2; s++) {
            bh8 af[4], bf_[4];
            #pragma unroll
            for (int i = 0; i < 4; i++) {
                const int row = wr + i * 16 + l16;
                const int jj = (s * 4 + quad) ^ (row & 7);
                af[i] = *(const bh8*)&As[row * 64 + jj * 8];   // A[row][k-chunk s*4+quad]
            }
            #pragma unroll
            for (int j = 0; j < 4; j++) {
                const int row = wc + j * 16 + l16;
                const int jj = (s * 4 + quad) ^ (row & 7);
                bf_[j] = *(const bh8*)&Bs[row * 64 + jj * 8];  // B[col][same k-chunk]
            }
            #pragma unroll
            for (int i = 0; i < 4; i++)
                #pragma unroll
                for (int j = 0; j < 4; j++)
                    acc[i][j] = __builtin_amdgcn_mfma_f32_16x16x32_bf16(af[i], bf_[j], acc[i][j], 0, 0, 0);
        }
        __syncthreads();   // reads done before next staging overwrites As/Bs
    }

    // epilogue: C/D layout col = lane&15, row = (lane>>4)*4 + reg  [m89-verified]
    float* Cb = out + (size_t)b * NN * HH + (size_t)bm * 128 * HH + bn * 128;
    const int rbase = wr + quad * 4;
    const int cbase = wc + l16;
    #pragma unroll
    for (int i = 0; i < 4; i++)
        #pragma unroll
        for (int j = 0; j < 4; j++)
            #pragma unroll
            for (int r = 0; r < 4; r++)
                Cb[(size_t)(rbase + i * 16 + r) * HH + cbase + j * 16] = acc[i][j][r];

    // s1/s2 partials: this tile's 128 f-columns dotted with wa1/wa2
    float w1j[4], w2j[4];
    #pragma unroll
    for (int j = 0; j < 4; j++) {
        w1j[j] = wa1[bn * 128 + cbase + j * 16];
        w2j[j] = wa2[bn * 128 + cbase + j * 16];
    }
    #pragma unroll
    for (int i = 0; i < 4; i++)
        #pragma unroll
        for (int r = 0; r < 4; r++) {
            float p1 = acc[i][0][r] * w1j[0] + acc[i][1][r] * w1j[1]
                     + acc[i][2][r] * w1j[2] + acc[i][3][r] * w1j[3];
            float p2 = acc[i][0][r] * w2j[0] + acc[i][1][r] * w2j[1]
                     + acc[i][2][r] * w2j[2] + acc[i][3][r] * w2j[3];
            p1 += __shfl_down(p1, 8, 16); p1 += __shfl_down(p1, 4, 16);
            p1 += __shfl_down(p1, 2, 16); p1 += __shfl_down(p1, 1, 16);
            p2 += __shfl_down(p2, 8, 16); p2 += __shfl_down(p2, 4, 16);
            p2 += __shfl_down(p2, 2, 16); p2 += __shfl_down(p2, 1, 16);
            if (l16 == 0) {
                const int n = b * NN + bm * 128 + rbase + i * 16 + r;
                atomicAdd(&s1[n], p1);
                atomicAdd(&s2[n], p2);
            }
        }
}

// ---------------- kernel 3: softmax -- one wave per row, mask from linear bits ----------------
// grid 4096 x 256. element j = lane*4 + i*256 + e -> word i*4+(lane>>4), bit (lane&15)*4+e.

__global__ __launch_bounds__(256) void softmax_kernel(const u64* __restrict__ bits,
                                                      const float* __restrict__ nl,
                                                      const float* __restrict__ s1,
                                                      const float* __restrict__ s2,
                                                      float* __restrict__ attn) {
    const int row = blockIdx.x * 4 + (threadIdx.x >> 6);
    const int lane = threadIdx.x & 63;
    const int b = row >> 10, n = row & (NN - 1);
    const u64* bwr = bits + (size_t)row * 16;
    const float* nlb = nl + (size_t)b * NN;
    const float* s2b = s2 + (size_t)b * NN;
    const float s1v = s1[row];
    const bool rowok = nlb[n] > 1e-6f;
    const int bitbase = (lane & 15) * 4;

    f4 sc[4];
    float mx = NEG_INF_;
    #pragma unroll
    for (int i = 0; i < 4; i++) {
        const int j = lane * 4 + i * 256;
        const float4 sv = *(const float4*)(s2b + j);
        const float4 nv = *(const float4*)(nlb + j);
        const u64 w64 = bwr[i * 4 + (lane >> 4)];
        const float zs[4] = { s1v + sv.x, s1v + sv.y, s1v + sv.z, s1v + sv.w };
        const float ns[4] = { nv.x, nv.y, nv.z, nv.w };
        #pragma unroll
        for (int e = 0; e < 4; e++) {
            const float z = zs[e];
            const float lr = z > 0.f ? z : SLOPE_ * z;
            const bool valid = rowok && ((w64 >> (bitbase + e)) & 1ull) && (ns[e] > 1e-6f);
            sc[i][e] = valid ? lr : NEG_INF_;
            mx = fmaxf(mx, sc[i][e]);
        }
    }
    mx = wave_max_all(mx);

    f4 ex[4];
    float sum = 0.f;
    #pragma unroll
    for (int i = 0; i < 4; i++)
        #pragma unroll
        for (int e = 0; e < 4; e++) {
            ex[i][e] = __expf(sc[i][e] - mx);   // all-masked row -> uniform, matches JAX
            sum += ex[i][e];
        }
    sum = wave_sum_all(sum);
    const float inv = 1.0f / sum;

    float* outr = attn + (size_t)row * NN;
    #pragma unroll
    for (int i = 0; i < 4; i++) {
        const int j = lane * 4 + i * 256;
        float4 o;
        o.x = ex[i][0] * inv; o.y = ex[i][1] * inv;
        o.z = ex[i][2] * inv; o.w = ex[i][3] * inv;
        *(float4*)(outr + j) = o;
    }
}

// ---------------- launch ----------------

extern "C" void kernel_launch(void* const* d_in, const int* in_sizes, int n_in,
                              void* d_out, int out_size, void* d_ws, size_t ws_size,
                              hipStream_t stream) {
    const float* x   = (const float*)d_in[0];   // (16,1024,768)
    const float* nl  = (const float*)d_in[1];   // (16,1024)
    const float* adj = (const float*)d_in[2];   // (16,1024,1024)
    const float* W   = (const float*)d_in[3];   // (768,768)
    const float* a   = (const float*)d_in[4];   // (1536,1)

    float* out = (float*)d_out;
    float* node_vec = out;                               // 16*1024*768 floats
    float* attn = out + (size_t)BB * NN * HH;            // 16*1024*1024 floats

    // scratch in d_ws (~448 MiB; we use ~64 MB):
    char* wsb = (char*)d_ws;
    float* wa1 = (float*)(wsb);                          // 3 KB
    float* wa2 = wa1 + HH;
    float* s1  = wa2 + HH;                               // 64 KB each
    float* s2  = s1 + BB * NN;
    u64*    bits = (u64*)(wsb + (1u << 20));             // 2 MB   @ 1 MB
    __bf16* xT   = (__bf16*)(wsb + (4u << 20));          // 24 MB  @ 4 MB
    __bf16* adjb = (__bf16*)(wsb + (32u << 20));         // 32 MB  @ 32 MB

    // DAG: prep_xt -> gemm (adjb, xT, wa, zeroed s) -> softmax (bits, s)
    hipLaunchKernelGGL(prep_xt_kernel, dim3(4096 + 24 * 32 * BB), dim3(256), 0, stream,
                       adj, W, a, x, bits, adjb, xT, wa1, wa2, s1, s2);
    hipLaunchKernelGGL(gemm_dense, dim3(6, 8, BB), dim3(256), 0, stream,
                       adjb, xT, wa1, wa2, node_vec, s1, s2);
    hipLaunchKernelGGL(softmax_kernel, dim3(4096), dim3(256), 0, stream, bits, nl, s1, s2, attn);
}

// Round 5
// 283.557 us; speedup vs baseline: 1.0073x; 1.0073x over previous
//
#include <hip/hip_runtime.h>
#include <hip/hip_bf16.h>

#define BB 16
#define NN 1024
#define HH 768
#define NEG_INF_ -9.0e15f
#define SLOPE_ 0.2f

typedef __bf16 bh8 __attribute__((ext_vector_type(8)));
typedef __bf16 bh4 __attribute__((ext_vector_type(4)));
typedef float f4 __attribute__((ext_vector_type(4)));
typedef unsigned int u32;
typedef unsigned long long u64;

// ---------------- wave-level reductions ----------------

__device__ __forceinline__ float wave_sum0(float v) {       // result valid in lane 0
    #pragma unroll
    for (int off = 32; off > 0; off >>= 1) v += __shfl_down(v, off, 64);
    return v;
}
__device__ __forceinline__ float wave_sum_all(float v) {
    #pragma unroll
    for (int off = 1; off < 64; off <<= 1) v += __shfl_xor(v, off, 64);
    return v;
}
__device__ __forceinline__ float wave_max_all(float v) {
    #pragma unroll
    for (int off = 1; off < 64; off <<= 1) v = fmaxf(v, __shfl_xor(v, off, 64));
    return v;
}

// ---------------- async global->LDS 16B ----------------

__device__ __forceinline__ void gl_lds16(const void* g, void* l) {
    __builtin_amdgcn_global_load_lds(
        (const __attribute__((address_space(1))) u32*)g,
        (__attribute__((address_space(3))) u32*)l, 16, 0, 0);
}

// ---------------- kernel 1: prep+xt merged ----------------
// grid 16384 x 256.
//  blocks 0..4095   : adj bit-pack (gemm A + softmax mask) + wa (blocks<192) + s-zero.
//  blocks 4096..    : xT transpose tiles (f32->bf16), 32x32, independent of the rest.
// (r4's adjb densify DELETED: dense A doubled gemm staging and lost 26 us.)

__global__ __launch_bounds__(256) void prep_xt_kernel(const float* __restrict__ adj,
                                                      const float* __restrict__ W,
                                                      const float* __restrict__ a,
                                                      const float* __restrict__ x,
                                                      u64* __restrict__ bits,
                                                      __bf16* __restrict__ xT,
                                                      float* __restrict__ wa1,
                                                      float* __restrict__ wa2,
                                                      float* __restrict__ s1,
                                                      float* __restrict__ s2) {
    __shared__ __bf16 T[32][36];
    const int bid = blockIdx.x;
    const int tid = threadIdx.x;
    const int wave = tid >> 6, lane = tid & 63;

    if (bid < 4096) {
        const int gid = bid * 256 + tid;
        if (gid < BB * NN) { s1[gid] = 0.f; s2[gid] = 0.f; }   // d_ws poisoned; gemm accumulates

        // ---- bit-pack one adj row per wave ----
        const int row = bid * 4 + wave;
        const float* ar = adj + (size_t)row * NN;
        const int seg = lane >> 4;
        const int sh = (lane & 15) * 4;
        #pragma unroll
        for (int i = 0; i < 4; i++) {
            const int j = lane * 4 + i * 256;           // 4 consecutive columns
            const float4 av = *(const float4*)(ar + j);
            u32 nib = (av.x > 1e-6f ? 1u : 0u) | (av.y > 1e-6f ? 2u : 0u)
                    | (av.z > 1e-6f ? 4u : 0u) | (av.w > 1e-6f ? 8u : 0u);
            u64 word = (u64)nib << sh;
            word |= __shfl_xor(word, 8, 16);
            word |= __shfl_xor(word, 4, 16);
            word |= __shfl_xor(word, 2, 16);
            word |= __shfl_xor(word, 1, 16);
            if ((lane & 15) == 0) bits[(size_t)row * 16 + i * 4 + seg] = word;
        }

        // ---- wa = W @ a1|a2 (one wave per f), blocks 0..191 only ----
        if (bid < 192) {
            const int f = bid * 4 + wave;
            const float* Wr = W + (size_t)f * HH;
            float v1 = 0.f, v2 = 0.f;
            #pragma unroll
            for (int i = 0; i < 3; i++) {
                const int h = lane * 4 + i * 256;
                const float4 w  = *(const float4*)(Wr + h);
                const float4 a1 = *(const float4*)(a + h);
                const float4 a2 = *(const float4*)(a + HH + h);
                v1 += w.x * a1.x + w.y * a1.y + w.z * a1.z + w.w * a1.w;
                v2 += w.x * a2.x + w.y * a2.y + w.z * a2.z + w.w * a2.w;
            }
            v1 = wave_sum0(v1);
            v2 = wave_sum0(v2);
            if (lane == 0) { wa1[f] = v1; wa2[f] = v2; }
        }
    } else {
        // ---- xT transpose tile ----
        const int u = bid - 4096;
        const int ht = u % 24;
        const int nt = (u / 24) & 31;
        const int b  = u / (24 * 32);
        const int r = tid >> 3;          // n within tile (0..31)
        const int c = (tid & 7) * 4;     // h within tile (0..28)
        const float4 v = *(const float4*)(x + ((size_t)b * NN + nt * 32 + r) * HH + ht * 32 + c);
        T[r][c + 0] = (__bf16)v.x; T[r][c + 1] = (__bf16)v.y;
        T[r][c + 2] = (__bf16)v.z; T[r][c + 3] = (__bf16)v.w;

        __syncthreads();
        const int h = tid >> 3;          // h within tile
        const int nc = (tid & 7) * 4;    // n within tile
        bh4 o = { T[nc + 0][h], T[nc + 1][h], T[nc + 2][h], T[nc + 3][h] };
        *(bh4*)(xT + ((size_t)b * HH + ht * 32 + h) * NN + nt * 32 + nc) = o;
    }
}

// ---------------- kernel 2: node_vec = adj @ x via bits-A + bf16-B MFMA, T3-min pipeline ----
// grid 768 x 256 (1-D, swizzled). Changes vs the r0/r3 core (which was staging-drain-bound:
// 2 barriers/K-step expose the full stage latency; r4 proved staging dominates):
//  * double-buffered B: stage tile w+1, compute tile w, ONE barrier per K-step ->
//    stage latency hides under the 32-MFMA cluster (T3-min recipe).
//  * XCD swizzle: the 8 bm-blocks sharing one (b,bn) B-panel get indices == same value
//    (mod 8) -> same XCD -> 7 of 8 panel stagings hit that XCD's L2 (~200cyc vs ~900 HBM),
//    exactly what a latency-bound stage loop needs. orig = g%8 + 8*bm + 64*(g/8), bijective.
//  * A-bits in REGISTERS: 4 u64/lane prefetched per step from L2-resident bits[] during
//    MFMAs; kills bitsL (17.4KB LDS) + its per-step ds_reads. LDS = 4 + 32 = 36.9 KB.
// Epilogue: C write + s1/s2 = node_vec @ wa (16-lane shuffle reduce -> 1 atomic/row-half).

__global__ __launch_bounds__(256) void gemm_bits(const u64* __restrict__ bits,
                                                 const __bf16* __restrict__ xT,
                                                 const float* __restrict__ wa1,
                                                 const float* __restrict__ wa2,
                                                 float* __restrict__ out,
                                                 float* __restrict__ s1,
                                                 float* __restrict__ s2) {
    __shared__ __bf16 LUT[256 * 8];       // 4 KB:  LUT[b][j] = (b>>j)&1
    __shared__ __bf16 Bs[2][128 * 64];    // 32 KB (double-buffered)

    // de-swizzle block id (see header)
    const int orig = blockIdx.x;
    const int g  = (orig >> 6) * 8 + (orig & 7);   // 0..95 = (b,bn) group, fixed per XCD
    const int bm = (orig >> 3) & 7;
    const int b  = g / 6;
    const int bn = g % 6;

    const int tid = threadIdx.x, lane = tid & 63, wave = tid >> 6;
    const int wr = (wave >> 1) << 6;
    const int wc = (wave & 1) << 6;
    const int quad = lane >> 4, l16 = lane & 15;

    // build LUT (one entry per thread); prologue barrier covers visibility
    {
        bh8 e;
        #pragma unroll
        for (int j = 0; j < 8; j++) e[j] = ((tid >> j) & 1) ? (__bf16)1.0f : (__bf16)0.0f;
        *(bh8*)&LUT[tid * 8] = e;
    }

    const __bf16* Xb = xT + ((size_t)b * HH + bn * 128) * NN;
    const u64* bgA = bits + ((size_t)b * NN + bm * 128) * 16;   // A bit rows, L2-resident

    f4 acc[4][4];
    #pragma unroll
    for (int i = 0; i < 4; i++)
        #pragma unroll
        for (int j = 0; j < 4; j++)
            acc[i][j] = (f4){0.f, 0.f, 0.f, 0.f};

    // per-lane A-word rows (fixed per lane): wr + i*16 + l16; word 0 now
    u64 awc[4];
    #pragma unroll
    for (int i = 0; i < 4; i++)
        awc[i] = bgA[(size_t)(wr + i * 16 + l16) * 16 + 0];

    // prologue: stage tile 0 into Bs[0]  (slot (r,j) <- global chunk j^(r&7))
    #pragma unroll
    for (int it = 0; it < 4; it++) {
        const int c = tid + 256 * it;
        const int r = c >> 3, j = c & 7, kc = j ^ (r & 7);
        gl_lds16(Xb + (size_t)r * NN + kc * 8, &Bs[0][r * 64 + j * 8]);
    }
    __syncthreads();   // LUT + tile0 visible

    for (int w = 0; w < 16; ++w) {
        const int cur = w & 1;
        u64 awn[4];
        // issue next tile's staging + next A-words BEFORE compute -> latency under MFMA
        if (w < 15) {
            const int kt = (w + 1) << 6;
            #pragma unroll
            for (int it = 0; it < 4; it++) {
                const int c = tid + 256 * it;
                const int r = c >> 3, j = c & 7, kc = j ^ (r & 7);
                gl_lds16(Xb + (size_t)r * NN + kt + kc * 8, &Bs[cur ^ 1][r * 64 + j * 8]);
            }
            #pragma unroll
            for (int i = 0; i < 4; i++)
                awn[i] = bgA[(size_t)(wr + i * 16 + l16) * 16 + w + 1];
        }

        #pragma unroll
        for (int s = 0; s < 2; s++) {
            bh8 af[4], bf_[4];
            #pragma unroll
            for (int i = 0; i < 4; i++) {
                const u32 byte = (u32)(awc[i] >> ((s * 4 + quad) * 8)) & 0xffu;
                af[i] = *(const bh8*)&LUT[byte * 8];       // k = w*64 + (s*4+quad)*8 + 0..7
            }
            #pragma unroll
            for (int j = 0; j < 4; j++) {
                const int row = wc + j * 16 + l16;
                const int jj = (s * 4 + quad) ^ (row & 7);
                bf_[j] = *(const bh8*)&Bs[cur][row * 64 + jj * 8];   // same k-chunk s*4+quad
            }
            #pragma unroll
            for (int i = 0; i < 4; i++)
                #pragma unroll
                for (int j = 0; j < 4; j++)
                    acc[i][j] = __builtin_amdgcn_mfma_f32_16x16x32_bf16(af[i], bf_[j], acc[i][j], 0, 0, 0);
        }
        // ONE barrier: its vmcnt(0)+lgkmcnt(0) drain covers (a) this wave's next-tile
        // staging landed, (b) all waves' reads of Bs[cur] done before it is re-staged
        __syncthreads();
        if (w < 15) {
            #pragma unroll
            for (int i = 0; i < 4; i++) awc[i] = awn[i];
        }
    }

    // epilogue: C/D layout col = lane&15, row = (lane>>4)*4 + reg  [m89-verified]
    float* Cb = out + (size_t)b * NN * HH + (size_t)bm * 128 * HH + bn * 128;
    const int rbase = wr + quad * 4;
    const int cbase = wc + l16;
    #pragma unroll
    for (int i = 0; i < 4; i++)
        #pragma unroll
        for (int j = 0; j < 4; j++)
            #pragma unroll
            for (int r = 0; r < 4; r++)
                Cb[(size_t)(rbase + i * 16 + r) * HH + cbase + j * 16] = acc[i][j][r];

    // s1/s2 partials: this tile's 128 f-columns dotted with wa1/wa2
    float w1j[4], w2j[4];
    #pragma unroll
    for (int j = 0; j < 4; j++) {
        w1j[j] = wa1[bn * 128 + cbase + j * 16];
        w2j[j] = wa2[bn * 128 + cbase + j * 16];
    }
    #pragma unroll
    for (int i = 0; i < 4; i++)
        #pragma unroll
        for (int r = 0; r < 4; r++) {
            float p1 = acc[i][0][r] * w1j[0] + acc[i][1][r] * w1j[1]
                     + acc[i][2][r] * w1j[2] + acc[i][3][r] * w1j[3];
            float p2 = acc[i][0][r] * w2j[0] + acc[i][1][r] * w2j[1]
                     + acc[i][2][r] * w2j[2] + acc[i][3][r] * w2j[3];
            p1 += __shfl_down(p1, 8, 16); p1 += __shfl_down(p1, 4, 16);
            p1 += __shfl_down(p1, 2, 16); p1 += __shfl_down(p1, 1, 16);
            p2 += __shfl_down(p2, 8, 16); p2 += __shfl_down(p2, 4, 16);
            p2 += __shfl_down(p2, 2, 16); p2 += __shfl_down(p2, 1, 16);
            if (l16 == 0) {
                const int n = b * NN + bm * 128 + rbase + i * 16 + r;
                atomicAdd(&s1[n], p1);
                atomicAdd(&s2[n], p2);
            }
        }
}

// ---------------- kernel 3: softmax -- one wave per row, mask from linear bits ----------------
// grid 4096 x 256. element j = lane*4 + i*256 + e -> word i*4+(lane>>4), bit (lane&15)*4+e.

__global__ __launch_bounds__(256) void softmax_kernel(const u64* __restrict__ bits,
                                                      const float* __restrict__ nl,
                                                      const float* __restrict__ s1,
                                                      const float* __restrict__ s2,
                                                      float* __restrict__ attn) {
    const int row = blockIdx.x * 4 + (threadIdx.x >> 6);
    const int lane = threadIdx.x & 63;
    const int b = row >> 10, n = row & (NN - 1);
    const u64* bwr = bits + (size_t)row * 16;
    const float* nlb = nl + (size_t)b * NN;
    const float* s2b = s2 + (size_t)b * NN;
    const float s1v = s1[row];
    const bool rowok = nlb[n] > 1e-6f;
    const int bitbase = (lane & 15) * 4;

    f4 sc[4];
    float mx = NEG_INF_;
    #pragma unroll
    for (int i = 0; i < 4; i++) {
        const int j = lane * 4 + i * 256;
        const float4 sv = *(const float4*)(s2b + j);
        const float4 nv = *(const float4*)(nlb + j);
        const u64 w64 = bwr[i * 4 + (lane >> 4)];
        const float zs[4] = { s1v + sv.x, s1v + sv.y, s1v + sv.z, s1v + sv.w };
        const float ns[4] = { nv.x, nv.y, nv.z, nv.w };
        #pragma unroll
        for (int e = 0; e < 4; e++) {
            const float z = zs[e];
            const float lr = z > 0.f ? z : SLOPE_ * z;
            const bool valid = rowok && ((w64 >> (bitbase + e)) & 1ull) && (ns[e] > 1e-6f);
            sc[i][e] = valid ? lr : NEG_INF_;
            mx = fmaxf(mx, sc[i][e]);
        }
    }
    mx = wave_max_all(mx);

    f4 ex[4];
    float sum = 0.f;
    #pragma unroll
    for (int i = 0; i < 4; i++)
        #pragma unroll
        for (int e = 0; e < 4; e++) {
            ex[i][e] = __expf(sc[i][e] - mx);   // all-masked row -> uniform, matches JAX
            sum += ex[i][e];
        }
    sum = wave_sum_all(sum);
    const float inv = 1.0f / sum;

    float* outr = attn + (size_t)row * NN;
    #pragma unroll
    for (int i = 0; i < 4; i++) {
        const int j = lane * 4 + i * 256;
        float4 o;
        o.x = ex[i][0] * inv; o.y = ex[i][1] * inv;
        o.z = ex[i][2] * inv; o.w = ex[i][3] * inv;
        *(float4*)(outr + j) = o;
    }
}

// ---------------- launch ----------------

extern "C" void kernel_launch(void* const* d_in, const int* in_sizes, int n_in,
                              void* d_out, int out_size, void* d_ws, size_t ws_size,
                              hipStream_t stream) {
    const float* x   = (const float*)d_in[0];   // (16,1024,768)
    const float* nl  = (const float*)d_in[1];   // (16,1024)
    const float* adj = (const float*)d_in[2];   // (16,1024,1024)
    const float* W   = (const float*)d_in[3];   // (768,768)
    const float* a   = (const float*)d_in[4];   // (1536,1)

    float* out = (float*)d_out;
    float* node_vec = out;                               // 16*1024*768 floats
    float* attn = out + (size_t)BB * NN * HH;            // 16*1024*1024 floats

    // scratch in d_ws (~448 MiB; we use ~28 MB):
    char* wsb = (char*)d_ws;
    float* wa1 = (float*)(wsb);                          // 3 KB
    float* wa2 = wa1 + HH;
    float* s1  = wa2 + HH;                               // 64 KB each
    float* s2  = s1 + BB * NN;
    u64*    bits = (u64*)(wsb + (1u << 20));             // 2 MB   @ 1 MB
    __bf16* xT   = (__bf16*)(wsb + (4u << 20));          // 24 MB  @ 4 MB

    // DAG: prep_xt -> gemm (bits, xT, wa, zeroed s) -> softmax (bits, s)
    hipLaunchKernelGGL(prep_xt_kernel, dim3(4096 + 24 * 32 * BB), dim3(256), 0, stream,
                       adj, W, a, x, bits, xT, wa1, wa2, s1, s2);
    hipLaunchKernelGGL(gemm_bits, dim3(768), dim3(256), 0, stream,
                       bits, xT, wa1, wa2, node_vec, s1, s2);
    hipLaunchKernelGGL(softmax_kernel, dim3(4096), dim3(256), 0, stream, bits, nl, s1, s2, attn);
}

// Round 6
// 265.958 us; speedup vs baseline: 1.0740x; 1.0662x over previous
//
#include <hip/hip_runtime.h>
#include <hip/hip_bf16.h>

#define BB 16
#define NN 1024
#define HH 768
#define NEG_INF_ -9.0e15f
#define SLOPE_ 0.2f

typedef __bf16 bh8 __attribute__((ext_vector_type(8)));
typedef __bf16 bh4 __attribute__((ext_vector_type(4)));
typedef float f4 __attribute__((ext_vector_type(4)));
typedef unsigned int u32;
typedef unsigned long long u64;

// ---------------- wave-level reductions ----------------

__device__ __forceinline__ float wave_sum0(float v) {       // result valid in lane 0
    #pragma unroll
    for (int off = 32; off > 0; off >>= 1) v += __shfl_down(v, off, 64);
    return v;
}
__device__ __forceinline__ float wave_sum_all(float v) {
    #pragma unroll
    for (int off = 1; off < 64; off <<= 1) v += __shfl_xor(v, off, 64);
    return v;
}
__device__ __forceinline__ float wave_max_all(float v) {
    #pragma unroll
    for (int off = 1; off < 64; off <<= 1) v = fmaxf(v, __shfl_xor(v, off, 64));
    return v;
}

// ---------------- async global->LDS 16B ----------------

__device__ __forceinline__ void gl_lds16(const void* g, void* l) {
    __builtin_amdgcn_global_load_lds(
        (const __attribute__((address_space(1))) u32*)g,
        (__attribute__((address_space(3))) u32*)l, 16, 0, 0);
}

// ---------------- kernel 1: prep+xt merged ----------------
// grid 16384 x 256.
//  blocks 0..4095   : adj bit-pack (gemm A + softmax mask) + wa (blocks<192) + s-zero.
//  blocks 4096..    : xT transpose tiles (f32->bf16), 32x32, independent of the rest.

__global__ __launch_bounds__(256) void prep_xt_kernel(const float* __restrict__ adj,
                                                      const float* __restrict__ W,
                                                      const float* __restrict__ a,
                                                      const float* __restrict__ x,
                                                      u64* __restrict__ bits,
                                                      __bf16* __restrict__ xT,
                                                      float* __restrict__ wa1,
                                                      float* __restrict__ wa2,
                                                      float* __restrict__ s1,
                                                      float* __restrict__ s2) {
    __shared__ __bf16 T[32][36];
    const int bid = blockIdx.x;
    const int tid = threadIdx.x;
    const int wave = tid >> 6, lane = tid & 63;

    if (bid < 4096) {
        const int gid = bid * 256 + tid;
        if (gid < BB * NN) { s1[gid] = 0.f; s2[gid] = 0.f; }   // d_ws poisoned; gemm accumulates

        // ---- bit-pack one adj row per wave ----
        const int row = bid * 4 + wave;
        const float* ar = adj + (size_t)row * NN;
        const int seg = lane >> 4;
        const int sh = (lane & 15) * 4;
        #pragma unroll
        for (int i = 0; i < 4; i++) {
            const int j = lane * 4 + i * 256;           // 4 consecutive columns
            const float4 av = *(const float4*)(ar + j);
            u32 nib = (av.x > 1e-6f ? 1u : 0u) | (av.y > 1e-6f ? 2u : 0u)
                    | (av.z > 1e-6f ? 4u : 0u) | (av.w > 1e-6f ? 8u : 0u);
            u64 word = (u64)nib << sh;
            word |= __shfl_xor(word, 8, 16);
            word |= __shfl_xor(word, 4, 16);
            word |= __shfl_xor(word, 2, 16);
            word |= __shfl_xor(word, 1, 16);
            if ((lane & 15) == 0) bits[(size_t)row * 16 + i * 4 + seg] = word;
        }

        // ---- wa = W @ a1|a2 (one wave per f), blocks 0..191 only ----
        if (bid < 192) {
            const int f = bid * 4 + wave;
            const float* Wr = W + (size_t)f * HH;
            float v1 = 0.f, v2 = 0.f;
            #pragma unroll
            for (int i = 0; i < 3; i++) {
                const int h = lane * 4 + i * 256;
                const float4 w  = *(const float4*)(Wr + h);
                const float4 a1 = *(const float4*)(a + h);
                const float4 a2 = *(const float4*)(a + HH + h);
                v1 += w.x * a1.x + w.y * a1.y + w.z * a1.z + w.w * a1.w;
                v2 += w.x * a2.x + w.y * a2.y + w.z * a2.z + w.w * a2.w;
            }
            v1 = wave_sum0(v1);
            v2 = wave_sum0(v2);
            if (lane == 0) { wa1[f] = v1; wa2[f] = v2; }
        }
    } else {
        // ---- xT transpose tile ----
        const int u = bid - 4096;
        const int ht = u % 24;
        const int nt = (u / 24) & 31;
        const int b  = u / (24 * 32);
        const int r = tid >> 3;          // n within tile (0..31)
        const int c = (tid & 7) * 4;     // h within tile (0..28)
        const float4 v = *(const float4*)(x + ((size_t)b * NN + nt * 32 + r) * HH + ht * 32 + c);
        T[r][c + 0] = (__bf16)v.x; T[r][c + 1] = (__bf16)v.y;
        T[r][c + 2] = (__bf16)v.z; T[r][c + 3] = (__bf16)v.w;

        __syncthreads();
        const int h = tid >> 3;          // h within tile
        const int nc = (tid & 7) * 4;    // n within tile
        bh4 o = { T[nc + 0][h], T[nc + 1][h], T[nc + 2][h], T[nc + 3][h] };
        *(bh4*)(xT + ((size_t)b * HH + ht * 32 + h) * NN + nt * 32 + nc) = o;
    }
}

// ---------------- kernel 2: node_vec = adj @ x -- bits-A + bf16-B MFMA, counted-vmcnt pipeline ----
// grid 768 x 256 (1-D, XCD-swizzled: the 8 bm-blocks sharing one (b,bn) B-panel land on one
// XCD -> panel re-stagings hit that XCD's L2). ROUND-0 compute core (LUT + bitsL-in-LDS,
// both loaded once; XOR-swizzled Bs slots) -- r5's uncoalesced per-lane A-register prefetch
// REVERTED. New vs r0: 2-deep B staging with RAW s_barrier + COUNTED s_waitcnt vmcnt(4)
// (T3+T4 minimum). r0/r5 used __syncthreads = vmcnt(0) drain -> every K-step serially paid
// the full stage latency (the documented m97-ceiling mechanism); here tile w+1 stays in
// flight across the compute of tile w and is only waited (vmcnt(4)) after the next stage
// issue. vmcnt is per-wave; each wave waits its own 4 loads, the barrier makes all waves'
// slots visible. Safety: every ds_read of Bs[cur] feeds an MFMA, so compiler-inserted
// lgkmcnt waits guarantee reads completed before barrier A -> restaging cannot race them.
// LDS = 4K LUT + 17.4K bitsL + 32K Bs[2] = 54,272 B -> exactly 3 blocks/CU.

#define BW 17   // u64 words per bits row in LDS: conflict-free across l16

__global__ __launch_bounds__(256) void gemm_bits(const u64* __restrict__ bits,
                                                 const __bf16* __restrict__ xT,
                                                 const float* __restrict__ wa1,
                                                 const float* __restrict__ wa2,
                                                 float* __restrict__ out,
                                                 float* __restrict__ s1,
                                                 float* __restrict__ s2) {
    __shared__ __bf16 LUT[256 * 8];       // 4 KB:  LUT[b][j] = (b>>j)&1
    __shared__ u64 bitsL[128 * BW];       // 17.4 KB
    __shared__ __bf16 Bs[2][128 * 64];    // 32 KB (double-buffered)

    // de-swizzle block id: orig = 64q + 8m + r -> g = 8q + r (b,bn group), bm = m. Bijective.
    const int orig = blockIdx.x;
    const int g  = (orig >> 6) * 8 + (orig & 7);
    const int bm = (orig >> 3) & 7;
    const int b  = g / 6;
    const int bn = g % 6;

    const int tid = threadIdx.x, lane = tid & 63, wave = tid >> 6;
    const int wr = (wave >> 1) << 6;
    const int wc = (wave & 1) << 6;
    const int quad = lane >> 4, l16 = lane & 15;

    // build LUT (one entry per thread)
    {
        bh8 e;
        #pragma unroll
        for (int j = 0; j < 8; j++) e[j] = ((tid >> j) & 1) ? (__bf16)1.0f : (__bf16)0.0f;
        *(bh8*)&LUT[tid * 8] = e;
    }
    // load A bitmask rows bm*128..+128 (16 KB contiguous), once
    {
        const u64* bg = bits + ((size_t)b * NN + bm * 128) * 16;
        #pragma unroll
        for (int q = 0; q < 8; q++) {
            const int gw = tid * 8 + q;                 // global word index
            bitsL[(gw >> 4) * BW + (gw & 15)] = bg[gw];
        }
    }

    const __bf16* Xb = xT + ((size_t)b * HH + bn * 128) * NN;

    // per-thread staging geometry: slot (r,j) <- global chunk j^(r&7); dest lane-linear
    const __bf16* sSrc[4]; int sOff[4];
    #pragma unroll
    for (int it = 0; it < 4; it++) {
        const int c = tid + 256 * it;
        const int r = c >> 3, j = c & 7, kc = j ^ (r & 7);
        sSrc[it] = Xb + (size_t)r * NN + kc * 8;
        sOff[it] = c * 8;                 // element offset (16B per thread-chunk)
    }

    f4 acc[4][4];
    #pragma unroll
    for (int i = 0; i < 4; i++)
        #pragma unroll
        for (int j = 0; j < 4; j++)
            acc[i][j] = (f4){0.f, 0.f, 0.f, 0.f};

    // prologue: stage tiles 0 and 1 (8 loads in flight), wait only tile 0
    #pragma unroll
    for (int it = 0; it < 4; it++) gl_lds16(sSrc[it] + 0,  &Bs[0][sOff[it]]);
    #pragma unroll
    for (int it = 0; it < 4; it++) gl_lds16(sSrc[it] + 64, &Bs[1][sOff[it]]);
    asm volatile("s_waitcnt lgkmcnt(0) vmcnt(4)" ::: "memory");  // LUT+bitsL stored; tile0 landed
    __builtin_amdgcn_s_barrier();
    asm volatile("" ::: "memory");

    for (int w = 0; w < 16; ++w) {
        const int cur = w & 1;

        u64 aw[4];
        #pragma unroll
        for (int i = 0; i < 4; i++)
            aw[i] = bitsL[(wr + i * 16 + l16) * BW + w];   // broadcast across quads, CF

        #pragma unroll
        for (int s = 0; s < 2; s++) {
            bh8 af[4], bf_[4];
            #pragma unroll
            for (int i = 0; i < 4; i++) {
                const u32 byte = (u32)(aw[i] >> ((s * 4 + quad) * 8)) & 0xffu;
                af[i] = *(const bh8*)&LUT[byte * 8];       // k = w*64 + (s*4+quad)*8 + 0..7
            }
            #pragma unroll
            for (int j = 0; j < 4; j++) {
                const int row = wc + j * 16 + l16;
                const int jj = (s * 4 + quad) ^ (row & 7);
                bf_[j] = *(const bh8*)&Bs[cur][row * 64 + jj * 8];   // same k-chunk s*4+quad
            }
            #pragma unroll
            for (int i = 0; i < 4; i++)
                #pragma unroll
                for (int j = 0; j < 4; j++)
                    acc[i][j] = __builtin_amdgcn_mfma_f32_16x16x32_bf16(af[i], bf_[j], acc[i][j], 0, 0, 0);
        }

        if (w < 14) {
            // barrier A: all waves' Bs[cur] reads done (they fed MFMAs -> lgkmcnt'd)
            __builtin_amdgcn_s_barrier();
            asm volatile("" ::: "memory");
            // restage Bs[cur] with tile w+2; outstanding: tile w+1 (4) + tile w+2 (4)
            const int kt = (w + 2) << 6;
            #pragma unroll
            for (int it = 0; it < 4; it++) gl_lds16(sSrc[it] + kt, &Bs[cur][sOff[it]]);
            // counted wait: tile w+1 landed, tile w+2 stays in flight (never vmcnt(0))
            asm volatile("s_waitcnt vmcnt(4)" ::: "memory");
            __builtin_amdgcn_s_barrier();
            asm volatile("" ::: "memory");
        } else if (w == 14) {
            // last handoff: nothing left to stage; drain tile 15
            asm volatile("s_waitcnt vmcnt(0)" ::: "memory");
            __builtin_amdgcn_s_barrier();
            asm volatile("" ::: "memory");
        }
    }

    // epilogue: C/D layout col = lane&15, row = (lane>>4)*4 + reg  [m89-verified]
    float* Cb = out + (size_t)b * NN * HH + (size_t)bm * 128 * HH + bn * 128;
    const int rbase = wr + quad * 4;
    const int cbase = wc + l16;
    #pragma unroll
    for (int i = 0; i < 4; i++)
        #pragma unroll
        for (int j = 0; j < 4; j++)
            #pragma unroll
            for (int r = 0; r < 4; r++)
                Cb[(size_t)(rbase + i * 16 + r) * HH + cbase + j * 16] = acc[i][j][r];

    // s1/s2 partials: this tile's 128 f-columns dotted with wa1/wa2
    float w1j[4], w2j[4];
    #pragma unroll
    for (int j = 0; j < 4; j++) {
        w1j[j] = wa1[bn * 128 + cbase + j * 16];
        w2j[j] = wa2[bn * 128 + cbase + j * 16];
    }
    #pragma unroll
    for (int i = 0; i < 4; i++)
        #pragma unroll
        for (int r = 0; r < 4; r++) {
            float p1 = acc[i][0][r] * w1j[0] + acc[i][1][r] * w1j[1]
                     + acc[i][2][r] * w1j[2] + acc[i][3][r] * w1j[3];
            float p2 = acc[i][0][r] * w2j[0] + acc[i][1][r] * w2j[1]
                     + acc[i][2][r] * w2j[2] + acc[i][3][r] * w2j[3];
            p1 += __shfl_down(p1, 8, 16); p1 += __shfl_down(p1, 4, 16);
            p1 += __shfl_down(p1, 2, 16); p1 += __shfl_down(p1, 1, 16);
            p2 += __shfl_down(p2, 8, 16); p2 += __shfl_down(p2, 4, 16);
            p2 += __shfl_down(p2, 2, 16); p2 += __shfl_down(p2, 1, 16);
            if (l16 == 0) {
                const int n = b * NN + bm * 128 + rbase + i * 16 + r;
                atomicAdd(&s1[n], p1);
                atomicAdd(&s2[n], p2);
            }
        }
}

// ---------------- kernel 3: softmax -- one wave per row, mask from linear bits ----------------
// grid 4096 x 256. element j = lane*4 + i*256 + e -> word i*4+(lane>>4), bit (lane&15)*4+e.

__global__ __launch_bounds__(256) void softmax_kernel(const u64* __restrict__ bits,
                                                      const float* __restrict__ nl,
                                                      const float* __restrict__ s1,
                                                      const float* __restrict__ s2,
                                                      float* __restrict__ attn) {
    const int row = blockIdx.x * 4 + (threadIdx.x >> 6);
    const int lane = threadIdx.x & 63;
    const int b = row >> 10, n = row & (NN - 1);
    const u64* bwr = bits + (size_t)row * 16;
    const float* nlb = nl + (size_t)b * NN;
    const float* s2b = s2 + (size_t)b * NN;
    const float s1v = s1[row];
    const bool rowok = nlb[n] > 1e-6f;
    const int bitbase = (lane & 15) * 4;

    f4 sc[4];
    float mx = NEG_INF_;
    #pragma unroll
    for (int i = 0; i < 4; i++) {
        const int j = lane * 4 + i * 256;
        const float4 sv = *(const float4*)(s2b + j);
        const float4 nv = *(const float4*)(nlb + j);
        const u64 w64 = bwr[i * 4 + (lane >> 4)];
        const float zs[4] = { s1v + sv.x, s1v + sv.y, s1v + sv.z, s1v + sv.w };
        const float ns[4] = { nv.x, nv.y, nv.z, nv.w };
        #pragma unroll
        for (int e = 0; e < 4; e++) {
            const float z = zs[e];
            const float lr = z > 0.f ? z : SLOPE_ * z;
            const bool valid = rowok && ((w64 >> (bitbase + e)) & 1ull) && (ns[e] > 1e-6f);
            sc[i][e] = valid ? lr : NEG_INF_;
            mx = fmaxf(mx, sc[i][e]);
        }
    }
    mx = wave_max_all(mx);

    f4 ex[4];
    float sum = 0.f;
    #pragma unroll
    for (int i = 0; i < 4; i++)
        #pragma unroll
        for (int e = 0; e < 4; e++) {
            ex[i][e] = __expf(sc[i][e] - mx);   // all-masked row -> uniform, matches JAX
            sum += ex[i][e];
        }
    sum = wave_sum_all(sum);
    const float inv = 1.0f / sum;

    float* outr = attn + (size_t)row * NN;
    #pragma unroll
    for (int i = 0; i < 4; i++) {
        const int j = lane * 4 + i * 256;
        float4 o;
        o.x = ex[i][0] * inv; o.y = ex[i][1] * inv;
        o.z = ex[i][2] * inv; o.w = ex[i][3] * inv;
        *(float4*)(outr + j) = o;
    }
}

// ---------------- launch ----------------

extern "C" void kernel_launch(void* const* d_in, const int* in_sizes, int n_in,
                              void* d_out, int out_size, void* d_ws, size_t ws_size,
                              hipStream_t stream) {
    const float* x   = (const float*)d_in[0];   // (16,1024,768)
    const float* nl  = (const float*)d_in[1];   // (16,1024)
    const float* adj = (const float*)d_in[2];   // (16,1024,1024)
    const float* W   = (const float*)d_in[3];   // (768,768)
    const float* a   = (const float*)d_in[4];   // (1536,1)

    float* out = (float*)d_out;
    float* node_vec = out;                               // 16*1024*768 floats
    float* attn = out + (size_t)BB * NN * HH;            // 16*1024*1024 floats

    // scratch in d_ws (~448 MiB; we use ~28 MB):
    char* wsb = (char*)d_ws;
    float* wa1 = (float*)(wsb);                          // 3 KB
    float* wa2 = wa1 + HH;
    float* s1  = wa2 + HH;                               // 64 KB each
    float* s2  = s1 + BB * NN;
    u64*    bits = (u64*)(wsb + (1u << 20));             // 2 MB   @ 1 MB
    __bf16* xT   = (__bf16*)(wsb + (4u << 20));          // 24 MB  @ 4 MB

    // DAG: prep_xt -> gemm (bits, xT, wa, zeroed s) -> softmax (bits, s)
    hipLaunchKernelGGL(prep_xt_kernel, dim3(4096 + 24 * 32 * BB), dim3(256), 0, stream,
                       adj, W, a, x, bits, xT, wa1, wa2, s1, s2);
    hipLaunchKernelGGL(gemm_bits, dim3(768), dim3(256), 0, stream,
                       bits, xT, wa1, wa2, node_vec, s1, s2);
    hipLaunchKernelGGL(softmax_kernel, dim3(4096), dim3(256), 0, stream, bits, nl, s1, s2, attn);
}

// Round 8
// 258.798 us; speedup vs baseline: 1.1037x; 1.0277x over previous
//
#include <hip/hip_runtime.h>
#include <hip/hip_bf16.h>

#define BB 16
#define NN 1024
#define HH 768
#define NEG_INF_ -9.0e15f
#define SLOPE_ 0.2f

typedef __bf16 bh8 __attribute__((ext_vector_type(8)));
typedef __bf16 bh4 __attribute__((ext_vector_type(4)));
typedef float f4 __attribute__((ext_vector_type(4)));
typedef unsigned int u32;
typedef unsigned long long u64;

// ---------------- wave-level reductions ----------------

__device__ __forceinline__ float wave_sum0(float v) {       // result valid in lane 0
    #pragma unroll
    for (int off = 32; off > 0; off >>= 1) v += __shfl_down(v, off, 64);
    return v;
}
__device__ __forceinline__ float wave_sum_all(float v) {
    #pragma unroll
    for (int off = 1; off < 64; off <<= 1) v += __shfl_xor(v, off, 64);
    return v;
}
__device__ __forceinline__ float wave_max_all(float v) {
    #pragma unroll
    for (int off = 1; off < 64; off <<= 1) v = fmaxf(v, __shfl_xor(v, off, 64));
    return v;
}

// ---------------- async global->LDS 16B ----------------

__device__ __forceinline__ void gl_lds16(const void* g, void* l) {
    __builtin_amdgcn_global_load_lds(
        (const __attribute__((address_space(1))) u32*)g,
        (__attribute__((address_space(3))) u32*)l, 16, 0, 0);
}

// ---------------- kernel 1: prep+xt merged ----------------
// grid 16384 x 256.
//  blocks 0..4095   : adj bit-pack (gemm A + softmax mask) + wa (blocks<192) + s-zero.
//                     adj loads NONTEMPORAL (read-once 64MB stream; keep L2 for x/xT).
//                     NOTE: nontemporal builtins need ext-vector types (f4), not HIP float4.
//  blocks 4096..    : xT transpose tiles (f32->bf16), 32x32, independent of the rest.

__global__ __launch_bounds__(256) void prep_xt_kernel(const float* __restrict__ adj,
                                                      const float* __restrict__ W,
                                                      const float* __restrict__ a,
                                                      const float* __restrict__ x,
                                                      u64* __restrict__ bits,
                                                      __bf16* __restrict__ xT,
                                                      float* __restrict__ wa1,
                                                      float* __restrict__ wa2,
                                                      float* __restrict__ s1,
                                                      float* __restrict__ s2) {
    __shared__ __bf16 T[32][36];
    const int bid = blockIdx.x;
    const int tid = threadIdx.x;
    const int wave = tid >> 6, lane = tid & 63;

    if (bid < 4096) {
        const int gid = bid * 256 + tid;
        if (gid < BB * NN) { s1[gid] = 0.f; s2[gid] = 0.f; }   // d_ws poisoned; gemm accumulates

        // ---- bit-pack one adj row per wave ----
        const int row = bid * 4 + wave;
        const float* ar = adj + (size_t)row * NN;
        const int seg = lane >> 4;
        const int sh = (lane & 15) * 4;
        #pragma unroll
        for (int i = 0; i < 4; i++) {
            const int j = lane * 4 + i * 256;           // 4 consecutive columns
            const f4 av = __builtin_nontemporal_load((const f4*)(ar + j));
            u32 nib = (av[0] > 1e-6f ? 1u : 0u) | (av[1] > 1e-6f ? 2u : 0u)
                    | (av[2] > 1e-6f ? 4u : 0u) | (av[3] > 1e-6f ? 8u : 0u);
            u64 word = (u64)nib << sh;
            word |= __shfl_xor(word, 8, 16);
            word |= __shfl_xor(word, 4, 16);
            word |= __shfl_xor(word, 2, 16);
            word |= __shfl_xor(word, 1, 16);
            if ((lane & 15) == 0) bits[(size_t)row * 16 + i * 4 + seg] = word;
        }

        // ---- wa = W @ a1|a2 (one wave per f), blocks 0..191 only ----
        if (bid < 192) {
            const int f = bid * 4 + wave;
            const float* Wr = W + (size_t)f * HH;
            float v1 = 0.f, v2 = 0.f;
            #pragma unroll
            for (int i = 0; i < 3; i++) {
                const int h = lane * 4 + i * 256;
                const float4 w  = *(const float4*)(Wr + h);
                const float4 a1 = *(const float4*)(a + h);
                const float4 a2 = *(const float4*)(a + HH + h);
                v1 += w.x * a1.x + w.y * a1.y + w.z * a1.z + w.w * a1.w;
                v2 += w.x * a2.x + w.y * a2.y + w.z * a2.z + w.w * a2.w;
            }
            v1 = wave_sum0(v1);
            v2 = wave_sum0(v2);
            if (lane == 0) { wa1[f] = v1; wa2[f] = v2; }
        }
    } else {
        // ---- xT transpose tile ----
        const int u = bid - 4096;
        const int ht = u % 24;
        const int nt = (u / 24) & 31;
        const int b  = u / (24 * 32);
        const int r = tid >> 3;          // n within tile (0..31)
        const int c = (tid & 7) * 4;     // h within tile (0..28)
        const float4 v = *(const float4*)(x + ((size_t)b * NN + nt * 32 + r) * HH + ht * 32 + c);
        T[r][c + 0] = (__bf16)v.x; T[r][c + 1] = (__bf16)v.y;
        T[r][c + 2] = (__bf16)v.z; T[r][c + 3] = (__bf16)v.w;

        __syncthreads();
        const int h = tid >> 3;          // h within tile
        const int nc = (tid & 7) * 4;    // n within tile
        bh4 o = { T[nc + 0][h], T[nc + 1][h], T[nc + 2][h], T[nc + 3][h] };
        *(bh4*)(xT + ((size_t)b * HH + ht * 32 + h) * NN + nt * 32 + nc) = o;
    }
}

// ---------------- kernel 2: node_vec = adj @ x -- bits-A + bf16-B MFMA, counted-vmcnt pipeline ----
// grid 768 x 256 (1-D, XCD-swizzled: the 8 bm-blocks sharing one (b,bn) B-panel land on one
// XCD -> panel re-stagings hit that XCD's L2). r6 WINNING STRUCTURE (283.6 -> 266.0 vs the
// __syncthreads version): 2-deep B staging, raw s_barrier + counted s_waitcnt vmcnt(4),
// never vmcnt(0) in steady state. r7 additions:
//  * T5 setprio(1) around the MFMA cluster -- the 3 blocks/CU are at different pipeline
//    phases (counted-vmcnt decouples them), so the CU scheduler can favor MFMA-phase waves.
//  * nontemporal C stores: node_vec (48MB) is never re-read; keep L2 for xT panels.
// LDS = 4K LUT + 17.4K bitsL + 32K Bs[2] = 54,272 B -> exactly 3 blocks/CU.

#define BW 17   // u64 words per bits row in LDS: conflict-free across l16

__global__ __launch_bounds__(256) void gemm_bits(const u64* __restrict__ bits,
                                                 const __bf16* __restrict__ xT,
                                                 const float* __restrict__ wa1,
                                                 const float* __restrict__ wa2,
                                                 float* __restrict__ out,
                                                 float* __restrict__ s1,
                                                 float* __restrict__ s2) {
    __shared__ __bf16 LUT[256 * 8];       // 4 KB:  LUT[b][j] = (b>>j)&1
    __shared__ u64 bitsL[128 * BW];       // 17.4 KB
    __shared__ __bf16 Bs[2][128 * 64];    // 32 KB (double-buffered)

    // de-swizzle block id: orig = 64q + 8m + r -> g = 8q + r (b,bn group), bm = m. Bijective.
    const int orig = blockIdx.x;
    const int g  = (orig >> 6) * 8 + (orig & 7);
    const int bm = (orig >> 3) & 7;
    const int b  = g / 6;
    const int bn = g % 6;

    const int tid = threadIdx.x, lane = tid & 63, wave = tid >> 6;
    const int wr = (wave >> 1) << 6;
    const int wc = (wave & 1) << 6;
    const int quad = lane >> 4, l16 = lane & 15;

    // build LUT (one entry per thread)
    {
        bh8 e;
        #pragma unroll
        for (int j = 0; j < 8; j++) e[j] = ((tid >> j) & 1) ? (__bf16)1.0f : (__bf16)0.0f;
        *(bh8*)&LUT[tid * 8] = e;
    }
    // load A bitmask rows bm*128..+128 (16 KB contiguous), once
    {
        const u64* bg = bits + ((size_t)b * NN + bm * 128) * 16;
        #pragma unroll
        for (int q = 0; q < 8; q++) {
            const int gw = tid * 8 + q;                 // global word index
            bitsL[(gw >> 4) * BW + (gw & 15)] = bg[gw];
        }
    }

    const __bf16* Xb = xT + ((size_t)b * HH + bn * 128) * NN;

    // per-thread staging geometry: slot (r,j) <- global chunk j^(r&7); dest lane-linear
    const __bf16* sSrc[4]; int sOff[4];
    #pragma unroll
    for (int it = 0; it < 4; it++) {
        const int c = tid + 256 * it;
        const int r = c >> 3, j = c & 7, kc = j ^ (r & 7);
        sSrc[it] = Xb + (size_t)r * NN + kc * 8;
        sOff[it] = c * 8;                 // element offset (16B per thread-chunk)
    }

    f4 acc[4][4];
    #pragma unroll
    for (int i = 0; i < 4; i++)
        #pragma unroll
        for (int j = 0; j < 4; j++)
            acc[i][j] = (f4){0.f, 0.f, 0.f, 0.f};

    // prologue: stage tiles 0 and 1 (8 loads in flight), wait only tile 0
    #pragma unroll
    for (int it = 0; it < 4; it++) gl_lds16(sSrc[it] + 0,  &Bs[0][sOff[it]]);
    #pragma unroll
    for (int it = 0; it < 4; it++) gl_lds16(sSrc[it] + 64, &Bs[1][sOff[it]]);
    asm volatile("s_waitcnt lgkmcnt(0) vmcnt(4)" ::: "memory");  // LUT+bitsL stored; tile0 landed
    __builtin_amdgcn_s_barrier();
    asm volatile("" ::: "memory");

    for (int w = 0; w < 16; ++w) {
        const int cur = w & 1;

        u64 aw[4];
        #pragma unroll
        for (int i = 0; i < 4; i++)
            aw[i] = bitsL[(wr + i * 16 + l16) * BW + w];   // broadcast across quads, CF

        __builtin_amdgcn_s_setprio(1);                      // T5: favor MFMA-phase waves
        #pragma unroll
        for (int s = 0; s < 2; s++) {
            bh8 af[4], bf_[4];
            #pragma unroll
            for (int i = 0; i < 4; i++) {
                const u32 byte = (u32)(aw[i] >> ((s * 4 + quad) * 8)) & 0xffu;
                af[i] = *(const bh8*)&LUT[byte * 8];       // k = w*64 + (s*4+quad)*8 + 0..7
            }
            #pragma unroll
            for (int j = 0; j < 4; j++) {
                const int row = wc + j * 16 + l16;
                const int jj = (s * 4 + quad) ^ (row & 7);
                bf_[j] = *(const bh8*)&Bs[cur][row * 64 + jj * 8];   // same k-chunk s*4+quad
            }
            #pragma unroll
            for (int i = 0; i < 4; i++)
                #pragma unroll
                for (int j = 0; j < 4; j++)
                    acc[i][j] = __builtin_amdgcn_mfma_f32_16x16x32_bf16(af[i], bf_[j], acc[i][j], 0, 0, 0);
        }
        __builtin_amdgcn_s_setprio(0);

        if (w < 14) {
            // barrier A: all waves' Bs[cur] reads done (they fed MFMAs -> lgkmcnt'd)
            __builtin_amdgcn_s_barrier();
            asm volatile("" ::: "memory");
            // restage Bs[cur] with tile w+2; outstanding: tile w+1 (4) + tile w+2 (4)
            const int kt = (w + 2) << 6;
            #pragma unroll
            for (int it = 0; it < 4; it++) gl_lds16(sSrc[it] + kt, &Bs[cur][sOff[it]]);
            // counted wait: tile w+1 landed, tile w+2 stays in flight (never vmcnt(0))
            asm volatile("s_waitcnt vmcnt(4)" ::: "memory");
            __builtin_amdgcn_s_barrier();
            asm volatile("" ::: "memory");
        } else if (w == 14) {
            // last handoff: nothing left to stage; drain tile 15
            asm volatile("s_waitcnt vmcnt(0)" ::: "memory");
            __builtin_amdgcn_s_barrier();
            asm volatile("" ::: "memory");
        }
    }

    // epilogue: C/D layout col = lane&15, row = (lane>>4)*4 + reg  [m89-verified]
    // nontemporal: node_vec is a pure output stream (never re-read) -> don't evict xT panels
    float* Cb = out + (size_t)b * NN * HH + (size_t)bm * 128 * HH + bn * 128;
    const int rbase = wr + quad * 4;
    const int cbase = wc + l16;
    #pragma unroll
    for (int i = 0; i < 4; i++)
        #pragma unroll
        for (int j = 0; j < 4; j++)
            #pragma unroll
            for (int r = 0; r < 4; r++)
                __builtin_nontemporal_store(acc[i][j][r],
                    &Cb[(size_t)(rbase + i * 16 + r) * HH + cbase + j * 16]);

    // s1/s2 partials: this tile's 128 f-columns dotted with wa1/wa2
    float w1j[4], w2j[4];
    #pragma unroll
    for (int j = 0; j < 4; j++) {
        w1j[j] = wa1[bn * 128 + cbase + j * 16];
        w2j[j] = wa2[bn * 128 + cbase + j * 16];
    }
    #pragma unroll
    for (int i = 0; i < 4; i++)
        #pragma unroll
        for (int r = 0; r < 4; r++) {
            float p1 = acc[i][0][r] * w1j[0] + acc[i][1][r] * w1j[1]
                     + acc[i][2][r] * w1j[2] + acc[i][3][r] * w1j[3];
            float p2 = acc[i][0][r] * w2j[0] + acc[i][1][r] * w2j[1]
                     + acc[i][2][r] * w2j[2] + acc[i][3][r] * w2j[3];
            p1 += __shfl_down(p1, 8, 16); p1 += __shfl_down(p1, 4, 16);
            p1 += __shfl_down(p1, 2, 16); p1 += __shfl_down(p1, 1, 16);
            p2 += __shfl_down(p2, 8, 16); p2 += __shfl_down(p2, 4, 16);
            p2 += __shfl_down(p2, 2, 16); p2 += __shfl_down(p2, 1, 16);
            if (l16 == 0) {
                const int n = b * NN + bm * 128 + rbase + i * 16 + r;
                atomicAdd(&s1[n], p1);
                atomicAdd(&s2[n], p2);
            }
        }
}

// ---------------- kernel 3: softmax -- one wave per row, mask from linear bits ----------------
// grid 4096 x 256. element j = lane*4 + i*256 + e -> word i*4+(lane>>4), bit (lane&15)*4+e.
// attn stores nontemporal (64MB pure output stream; f4 ext-vector for the builtin).

__global__ __launch_bounds__(256) void softmax_kernel(const u64* __restrict__ bits,
                                                      const float* __restrict__ nl,
                                                      const float* __restrict__ s1,
                                                      const float* __restrict__ s2,
                                                      float* __restrict__ attn) {
    const int row = blockIdx.x * 4 + (threadIdx.x >> 6);
    const int lane = threadIdx.x & 63;
    const int b = row >> 10, n = row & (NN - 1);
    const u64* bwr = bits + (size_t)row * 16;
    const float* nlb = nl + (size_t)b * NN;
    const float* s2b = s2 + (size_t)b * NN;
    const float s1v = s1[row];
    const bool rowok = nlb[n] > 1e-6f;
    const int bitbase = (lane & 15) * 4;

    f4 sc[4];
    float mx = NEG_INF_;
    #pragma unroll
    for (int i = 0; i < 4; i++) {
        const int j = lane * 4 + i * 256;
        const float4 sv = *(const float4*)(s2b + j);
        const float4 nv = *(const float4*)(nlb + j);
        const u64 w64 = bwr[i * 4 + (lane >> 4)];
        const float zs[4] = { s1v + sv.x, s1v + sv.y, s1v + sv.z, s1v + sv.w };
        const float ns[4] = { nv.x, nv.y, nv.z, nv.w };
        #pragma unroll
        for (int e = 0; e < 4; e++) {
            const float z = zs[e];
            const float lr = z > 0.f ? z : SLOPE_ * z;
            const bool valid = rowok && ((w64 >> (bitbase + e)) & 1ull) && (ns[e] > 1e-6f);
            sc[i][e] = valid ? lr : NEG_INF_;
            mx = fmaxf(mx, sc[i][e]);
        }
    }
    mx = wave_max_all(mx);

    f4 ex[4];
    float sum = 0.f;
    #pragma unroll
    for (int i = 0; i < 4; i++)
        #pragma unroll
        for (int e = 0; e < 4; e++) {
            ex[i][e] = __expf(sc[i][e] - mx);   // all-masked row -> uniform, matches JAX
            sum += ex[i][e];
        }
    sum = wave_sum_all(sum);
    const float inv = 1.0f / sum;

    float* outr = attn + (size_t)row * NN;
    #pragma unroll
    for (int i = 0; i < 4; i++) {
        const int j = lane * 4 + i * 256;
        f4 o;
        o[0] = ex[i][0] * inv; o[1] = ex[i][1] * inv;
        o[2] = ex[i][2] * inv; o[3] = ex[i][3] * inv;
        __builtin_nontemporal_store(o, (f4*)(outr + j));
    }
}

// ---------------- launch ----------------

extern "C" void kernel_launch(void* const* d_in, const int* in_sizes, int n_in,
                              void* d_out, int out_size, void* d_ws, size_t ws_size,
                              hipStream_t stream) {
    const float* x   = (const float*)d_in[0];   // (16,1024,768)
    const float* nl  = (const float*)d_in[1];   // (16,1024)
    const float* adj = (const float*)d_in[2];   // (16,1024,1024)
    const float* W   = (const float*)d_in[3];   // (768,768)
    const float* a   = (const float*)d_in[4];   // (1536,1)

    float* out = (float*)d_out;
    float* node_vec = out;                               // 16*1024*768 floats
    float* attn = out + (size_t)BB * NN * HH;            // 16*1024*1024 floats

    // scratch in d_ws (~448 MiB; we use ~28 MB):
    char* wsb = (char*)d_ws;
    float* wa1 = (float*)(wsb);                          // 3 KB
    float* wa2 = wa1 + HH;
    float* s1  = wa2 + HH;                               // 64 KB each
    float* s2  = s1 + BB * NN;
    u64*    bits = (u64*)(wsb + (1u << 20));             // 2 MB   @ 1 MB
    __bf16* xT   = (__bf16*)(wsb + (4u << 20));          // 24 MB  @ 4 MB

    // DAG: prep_xt -> gemm (bits, xT, wa, zeroed s) -> softmax (bits, s)
    hipLaunchKernelGGL(prep_xt_kernel, dim3(4096 + 24 * 32 * BB), dim3(256), 0, stream,
                       adj, W, a, x, bits, xT, wa1, wa2, s1, s2);
    hipLaunchKernelGGL(gemm_bits, dim3(768), dim3(256), 0, stream,
                       bits, xT, wa1, wa2, node_vec, s1, s2);
    hipLaunchKernelGGL(softmax_kernel, dim3(4096), dim3(256), 0, stream, bits, nl, s1, s2, attn);
}